// Round 5
// baseline (49.597 us; speedup 1.0000x reference)
//
#include <hip/hip_runtime.h>
#include <hip/hip_bf16.h>

constexpr int HIDDEN = 256;
constexpr int BAG    = 32;
constexpr int FEAT   = 41025;   // FEATURE_COUNT + 1 (includes zero pad row)
constexpr int NJ     = 64;      // P columns: [0:32]=us-proj, [32:64]=them-proj

// ---------- k0: P[f][j] = dot(emb[f], W2d[j]),  W2d[j] = fc1_w[j&31][(j>>5)*256 : +256]
// Whole W lives in LDS (staged once, coalesced, conflict-free) -> the K loop has
// NO barriers, so e4 global loads and w4 LDS reads pipeline freely.
// 64 rows x 64 cols per block; thread (rg,jg) = rows f0+rg*4+i, cols j=jg+16*ii.
__global__ __launch_bounds__(256, 2) void k0_project(
    const float* __restrict__ emb,
    const float* __restrict__ fc1_w,
    float*       __restrict__ P)
{
    __shared__ float4 w_lds[64][65];    // [col j][k-float4]; 65 pad -> (jg+kq)%8 banks

    const int tid = threadIdx.x;
    const int rg  = tid >> 4;           // 0..15
    const int jg  = tid & 15;           // 0..15
    const int f0  = blockIdx.x * 64;

    // ---- stage ALL of W once: 4096 float4s, fully coalesced global reads,
    //      conflict-free ds_write_b128 (addr%8 = (j + kq)%8 spreads across lanes)
    const float4* w4src = reinterpret_cast<const float4*>(fc1_w);
#pragma unroll
    for (int s = 0; s < 16; ++s) {
        const int idx4 = s * 256 + tid;        // 0..4095
        const int jr   = idx4 >> 7;            // fc1_w row 0..31
        const int kc4  = idx4 & 127;           // float4 within that row
        const int j    = jr + ((kc4 >= 64) ? 32 : 0);  // W2d column
        const int kq   = kc4 & 63;             // k-float4 within column
        w_lds[j][kq] = w4src[idx4];
    }

    const float4* emb4 = reinterpret_cast<const float4*>(emb);
    const float4* rowp[4];
#pragma unroll
    for (int i = 0; i < 4; ++i) {
        int f = f0 + rg * 4 + i;
        if (f >= FEAT) f = FEAT - 1;           // clamp; extra rows not stored
        rowp[i] = emb4 + (size_t)f * 64;
    }

    float acc[4][4];
#pragma unroll
    for (int i = 0; i < 4; ++i)
#pragma unroll
        for (int ii = 0; ii < 4; ++ii) acc[i][ii] = 0.f;

    __syncthreads();                            // the ONLY barrier

#pragma unroll 8
    for (int kq = 0; kq < 64; ++kq) {
        float4 e4[4], w4[4];
#pragma unroll
        for (int i = 0; i < 4; ++i)
            e4[i] = rowp[i][kq];                // 4 distinct addrs/wave (16-lane bcast)
#pragma unroll
        for (int ii = 0; ii < 4; ++ii)
            w4[ii] = w_lds[jg + 16 * ii][kq];   // conflict-free
#pragma unroll
        for (int i = 0; i < 4; ++i) {
            const float ek0 = e4[i].x, ek1 = e4[i].y, ek2 = e4[i].z, ek3 = e4[i].w;
#pragma unroll
            for (int ii = 0; ii < 4; ++ii) {
                acc[i][ii] += ek0 * w4[ii].x;
                acc[i][ii] += ek1 * w4[ii].y;
                acc[i][ii] += ek2 * w4[ii].z;
                acc[i][ii] += ek3 * w4[ii].w;
            }
        }
    }

#pragma unroll
    for (int i = 0; i < 4; ++i) {
        const int f = f0 + rg * 4 + i;
        if (f < FEAT) {
#pragma unroll
            for (int ii = 0; ii < 4; ++ii)
                P[(size_t)f * NJ + jg + 16 * ii] = acc[i][ii];  // 4x 64B segments/wave
        }
    }
}

// ---------- k1: gather P rows (128 B each) + fused MLP. One wave per batch row.
__global__ __launch_bounds__(256) void k1_gather_mlp(
    const int*   __restrict__ us,
    const int*   __restrict__ them,
    const float* __restrict__ P,
    const float* __restrict__ b1,
    const float* __restrict__ w2, const float* __restrict__ b2,
    const float* __restrict__ w3, const float* __restrict__ b3,
    float*       __restrict__ out)
{
    __shared__ float w2_lds[32][33];
    __shared__ float y1_lds[4][32];

    const int tid  = threadIdx.x;
    const int wave = tid >> 6;
    const int lane = tid & 63;

    for (int k = tid; k < 32 * 32; k += 256)
        w2_lds[k >> 5][k & 31] = w2[k];
    __syncthreads();

    const int row = blockIdx.x * 4 + wave;
    int idx;
    {
        const int* up = us   + (size_t)row * BAG;
        const int* tp = them + (size_t)row * BAG;
        idx = (lane < BAG) ? up[lane] : tp[lane - BAG];
    }

    // lane j<32 accumulates us-part col j; lane 32+j accumulates them-part col 32+j
    float acc = 0.f;
    const int srcbase = lane & 32;
#pragma unroll
    for (int i = 0; i < BAG; ++i) {
        const int f = __shfl(idx, srcbase + i);
        acc += P[(size_t)f * NJ + lane];
    }
    acc += __shfl_xor(acc, 32);            // lane j<32: full fc1_out[j] - b1[j]

    if (lane < 32)
        y1_lds[wave][lane] = fminf(fmaxf(acc + b1[lane], 0.f), 1.f);
    __syncthreads();

    float r3 = 0.f;
    if (lane < 32) {
        float s = b2[lane];
#pragma unroll
        for (int k = 0; k < 32; ++k) s += y1_lds[wave][k] * w2_lds[lane][k];
        r3 = fminf(fmaxf(s, 0.f), 1.f) * w3[lane];
    }
    r3 += __shfl_xor(r3, 16); r3 += __shfl_xor(r3, 8); r3 += __shfl_xor(r3, 4);
    r3 += __shfl_xor(r3, 2);  r3 += __shfl_xor(r3, 1);
    if (lane == 0) out[row] = tanhf(r3 + b3[0]);
}

// ---------- fallback: R0 monolithic kernel (if ws too small) ----------
__global__ __launch_bounds__(256) void nnue_fused(
    const int*   __restrict__ us,
    const int*   __restrict__ them,
    const float* __restrict__ emb,
    const float* __restrict__ w1, const float* __restrict__ b1,
    const float* __restrict__ w2, const float* __restrict__ b2,
    const float* __restrict__ w3, const float* __restrict__ b3,
    float*       __restrict__ out)
{
    __shared__ float x_lds[4][2 * HIDDEN];
    __shared__ float y1_lds[4][32];
    __shared__ float y2_lds[4][32];

    const int tid  = threadIdx.x;
    const int wave = tid >> 6;
    const int lane = tid & 63;
    const int row  = blockIdx.x * 4 + wave;

    int myidx;
    {
        const int* up = us   + (size_t)row * BAG;
        const int* tp = them + (size_t)row * BAG;
        myidx = (lane < BAG) ? up[lane] : tp[lane - BAG];
    }
    const float4* emb4 = reinterpret_cast<const float4*>(emb);
    float4 accU = make_float4(0.f, 0.f, 0.f, 0.f);
    float4 accT = make_float4(0.f, 0.f, 0.f, 0.f);
#pragma unroll
    for (int i = 0; i < BAG; ++i) {
        const int iu = __shfl(myidx, i);
        const int it = __shfl(myidx, BAG + i);
        const float4 vu = emb4[(size_t)iu * (HIDDEN / 4) + lane];
        const float4 vt = emb4[(size_t)it * (HIDDEN / 4) + lane];
        accU.x += vu.x; accU.y += vu.y; accU.z += vu.z; accU.w += vu.w;
        accT.x += vt.x; accT.y += vt.y; accT.z += vt.z; accT.w += vt.w;
    }
    {
        float4* xv = reinterpret_cast<float4*>(&x_lds[wave][0]);
        xv[lane]      = accU;
        xv[64 + lane] = accT;
    }
    __syncthreads();
    {
        const int r    = tid >> 6;
        const int sub  = tid & 63;
        const int j    = sub >> 1;
        const int half = sub & 1;
        const float4* xr = reinterpret_cast<const float4*>(&x_lds[r][0]) + half * 64;
        const float4* wr = reinterpret_cast<const float4*>(w1 + (size_t)j * (2 * HIDDEN)) + half * 64;
        float s = 0.f;
#pragma unroll 8
        for (int k = 0; k < 64; ++k) {
            const float4 xk = xr[k];
            const float4 wk = wr[k];
            s += xk.x * wk.x + xk.y * wk.y + xk.z * wk.z + xk.w * wk.w;
        }
        s += __shfl_xor(s, 1);
        if (half == 0) { s += b1[j]; y1_lds[r][j] = fminf(fmaxf(s, 0.f), 1.f); }
    }
    __syncthreads();
    if (tid < 4 * 32) {
        const int r = tid >> 5;
        const int j = tid & 31;
        const float* wr = w2 + j * 32;
        float s = b2[j];
#pragma unroll
        for (int k = 0; k < 32; ++k) s += y1_lds[r][k] * wr[k];
        y2_lds[r][j] = fminf(fmaxf(s, 0.f), 1.f);
    }
    __syncthreads();
    if (tid < 4) {
        const int r = tid;
        float s = b3[0];
#pragma unroll
        for (int k = 0; k < 32; ++k) s += y2_lds[r][k] * w3[k];
        out[blockIdx.x * 4 + r] = tanhf(s);
    }
}

extern "C" void kernel_launch(void* const* d_in, const int* in_sizes, int n_in,
                              void* d_out, int out_size, void* d_ws, size_t ws_size,
                              hipStream_t stream) {
    const int*   us   = (const int*)  d_in[0];
    const int*   them = (const int*)  d_in[1];
    const float* emb  = (const float*)d_in[2];
    const float* w1   = (const float*)d_in[3];
    const float* b1   = (const float*)d_in[4];
    const float* w2   = (const float*)d_in[5];
    const float* b2   = (const float*)d_in[6];
    const float* w3   = (const float*)d_in[7];
    const float* b3   = (const float*)d_in[8];
    float* out = (float*)d_out;

    const int batch = in_sizes[0] / BAG;                    // 8192
    const size_t p_bytes = (size_t)FEAT * NJ * sizeof(float);  // 10.5 MB

    if (ws_size >= p_bytes) {
        float* P = (float*)d_ws;
        const int grid0 = (FEAT + 63) / 64;                 // 642
        k0_project<<<grid0, 256, 0, stream>>>(emb, w1, P);
        k1_gather_mlp<<<batch / 4, 256, 0, stream>>>(us, them, P,
                                                     b1, w2, b2, w3, b3, out);
    } else {
        nnue_fused<<<(batch + 3) / 4, 256, 0, stream>>>(us, them, emb,
                                                        w1, b1, w2, b2, w3, b3, out);
    }
}

// Round 7
// 28.930 us; speedup vs baseline: 1.7144x; 1.7144x over previous
//
#include <hip/hip_runtime.h>
#include <hip/hip_bf16.h>

constexpr int HIDDEN = 256;
constexpr int BAG    = 32;
constexpr int FEAT   = 41025;   // FEATURE_COUNT + 1 (includes zero pad row)
constexpr int NJ     = 64;      // P columns: [0:32]=us-proj, [32:64]=them-proj
constexpr int LDSS   = 264;     // ushort stride per LDS row (256 + 8 pad)

using bf16x8 = __attribute__((ext_vector_type(8))) short;
using f32x4  = __attribute__((ext_vector_type(4))) float;

__device__ inline unsigned short f2bf(float f) {   // fp32 -> bf16, round-nearest-even
    union { float f; unsigned u; } x; x.f = f;
    return (unsigned short)((x.u + 0x7FFFu + ((x.u >> 16) & 1u)) >> 16);
}

// ---------- k0: P = emb @ W2d via bf16 MFMA (fp32 accumulate) ----------
// W2d[k][j] = fc1_w[j&31][(j>>5)*256 + k].  Block = 64 rows x 64 cols, 4 waves.
// Stage emb rows + fc1_w -> bf16 LDS (coalesced, full); 1 barrier; 8 k-steps.
__global__ __launch_bounds__(256, 2) void k0_project_mfma(
    const float* __restrict__ emb,
    const float* __restrict__ fc1_w,
    float*       __restrict__ P)
{
    __shared__ unsigned short a_lds[64 * LDSS];   // A: [row][k] bf16
    __shared__ unsigned short b_lds[64 * LDSS];   // B: [n(col j)][k] bf16

    const int tid = threadIdx.x;
    const int f0  = blockIdx.x * 64;
    const float4* emb4 = reinterpret_cast<const float4*>(emb);
    const float4* w4   = reinterpret_cast<const float4*>(fc1_w);

    // ---- stage A: emb[f0..f0+64)[0..256) -> bf16. 64 rows x 64 float4 = 4096.
#pragma unroll
    for (int s = 0; s < 16; ++s) {
        const int idx4 = s * 256 + tid;        // 0..4095
        const int row  = idx4 >> 6;            // 64 float4s per emb row
        const int kq4  = idx4 & 63;
        int grow = f0 + row; if (grow >= FEAT) grow = FEAT - 1;   // clamp (no OOB)
        const float4 v = emb4[(size_t)grow * 64 + kq4];
        ushort4 b; b.x = f2bf(v.x); b.y = f2bf(v.y); b.z = f2bf(v.z); b.w = f2bf(v.w);
        *reinterpret_cast<ushort4*>(&a_lds[row * LDSS + kq4 * 4]) = b;
    }
    // ---- stage B: fc1_w (32x512 fp32 = 4096 float4) -> b_lds[j][k] bf16
#pragma unroll
    for (int s = 0; s < 16; ++s) {
        const int idx4 = s * 256 + tid;
        const int jr  = idx4 >> 7;            // fc1_w row 0..31 (128 float4/row)
        const int kc4 = idx4 & 127;           // float4 within that row
        const int j   = jr + ((kc4 >= 64) ? 32 : 0);  // W2d column
        const int k4  = kc4 & 63;
        const float4 v = w4[idx4];
        ushort4 b; b.x = f2bf(v.x); b.y = f2bf(v.y); b.z = f2bf(v.z); b.w = f2bf(v.w);
        *reinterpret_cast<ushort4*>(&b_lds[j * LDSS + k4 * 4]) = b;
    }
    __syncthreads();

    const int lane = tid & 63, wave = tid >> 6;
    const int g = lane >> 4, ml = lane & 15;
    const int mw = wave * 16;                  // wave's 16 rows

    f32x4 acc[4] = {{0.f,0.f,0.f,0.f},{0.f,0.f,0.f,0.f},
                    {0.f,0.f,0.f,0.f},{0.f,0.f,0.f,0.f}};
#pragma unroll
    for (int kt = 0; kt < 8; ++kt) {           // K = 8 x 32
        const bf16x8 af = *reinterpret_cast<const bf16x8*>(
            &a_lds[(mw + ml) * LDSS + kt * 32 + g * 8]);
#pragma unroll
        for (int nt = 0; nt < 4; ++nt) {
            const bf16x8 bf = *reinterpret_cast<const bf16x8*>(
                &b_lds[(nt * 16 + ml) * LDSS + kt * 32 + g * 8]);
            acc[nt] = __builtin_amdgcn_mfma_f32_16x16x32_bf16(af, bf, acc[nt], 0, 0, 0);
        }
    }

    // D layout: row = g*4 + r, col = ml (verified C/D mapping)
#pragma unroll
    for (int nt = 0; nt < 4; ++nt) {
#pragma unroll
        for (int r = 0; r < 4; ++r) {
            const int f = f0 + mw + g * 4 + r;
            if (f < FEAT)
                P[(size_t)f * NJ + nt * 16 + ml] = acc[nt][r];
        }
    }
}

// ---------- k1: gather P rows (128 B each) + fused MLP. One wave per batch row.
__global__ __launch_bounds__(256) void k1_gather_mlp(
    const int*   __restrict__ us,
    const int*   __restrict__ them,
    const float* __restrict__ P,
    const float* __restrict__ b1,
    const float* __restrict__ w2, const float* __restrict__ b2,
    const float* __restrict__ w3, const float* __restrict__ b3,
    float*       __restrict__ out)
{
    __shared__ float w2_lds[32][33];
    __shared__ float y1_lds[4][32];

    const int tid  = threadIdx.x;
    const int wave = tid >> 6;
    const int lane = tid & 63;

    for (int k = tid; k < 32 * 32; k += 256)
        w2_lds[k >> 5][k & 31] = w2[k];
    __syncthreads();

    const int row = blockIdx.x * 4 + wave;
    int idx;
    {
        const int* up = us   + (size_t)row * BAG;
        const int* tp = them + (size_t)row * BAG;
        idx = (lane < BAG) ? up[lane] : tp[lane - BAG];
    }

    float acc = 0.f;
    const int srcbase = lane & 32;
#pragma unroll
    for (int i = 0; i < BAG; ++i) {
        const int f = __shfl(idx, srcbase + i);
        acc += P[(size_t)f * NJ + lane];
    }
    acc += __shfl_xor(acc, 32);

    if (lane < 32)
        y1_lds[wave][lane] = fminf(fmaxf(acc + b1[lane], 0.f), 1.f);
    __syncthreads();

    float r3 = 0.f;
    if (lane < 32) {
        float s = b2[lane];
#pragma unroll
        for (int k = 0; k < 32; ++k) s += y1_lds[wave][k] * w2_lds[lane][k];
        r3 = fminf(fmaxf(s, 0.f), 1.f) * w3[lane];
    }
    r3 += __shfl_xor(r3, 16); r3 += __shfl_xor(r3, 8); r3 += __shfl_xor(r3, 4);
    r3 += __shfl_xor(r3, 2);  r3 += __shfl_xor(r3, 1);
    if (lane == 0) out[row] = tanhf(r3 + b3[0]);
}

// ---------- fallback: R0 monolithic kernel (if ws too small) ----------
__global__ __launch_bounds__(256) void nnue_fused(
    const int*   __restrict__ us,
    const int*   __restrict__ them,
    const float* __restrict__ emb,
    const float* __restrict__ w1, const float* __restrict__ b1,
    const float* __restrict__ w2, const float* __restrict__ b2,
    const float* __restrict__ w3, const float* __restrict__ b3,
    float*       __restrict__ out)
{
    __shared__ float x_lds[4][2 * HIDDEN];
    __shared__ float y1_lds[4][32];
    __shared__ float y2_lds[4][32];

    const int tid  = threadIdx.x;
    const int wave = tid >> 6;
    const int lane = tid & 63;
    const int row  = blockIdx.x * 4 + wave;

    int myidx;
    {
        const int* up = us   + (size_t)row * BAG;
        const int* tp = them + (size_t)row * BAG;
        myidx = (lane < BAG) ? up[lane] : tp[lane - BAG];
    }
    const float4* emb4 = reinterpret_cast<const float4*>(emb);
    float4 accU = make_float4(0.f, 0.f, 0.f, 0.f);
    float4 accT = make_float4(0.f, 0.f, 0.f, 0.f);
#pragma unroll
    for (int i = 0; i < BAG; ++i) {
        const int iu = __shfl(myidx, i);
        const int it = __shfl(myidx, BAG + i);
        const float4 vu = emb4[(size_t)iu * (HIDDEN / 4) + lane];
        const float4 vt = emb4[(size_t)it * (HIDDEN / 4) + lane];
        accU.x += vu.x; accU.y += vu.y; accU.z += vu.z; accU.w += vu.w;
        accT.x += vt.x; accT.y += vt.y; accT.z += vt.z; accT.w += vt.w;
    }
    {
        float4* xv = reinterpret_cast<float4*>(&x_lds[wave][0]);
        xv[lane]      = accU;
        xv[64 + lane] = accT;
    }
    __syncthreads();
    {
        const int r    = tid >> 6;
        const int sub  = tid & 63;
        const int j    = sub >> 1;
        const int half = sub & 1;
        const float4* xr = reinterpret_cast<const float4*>(&x_lds[r][0]) + half * 64;
        const float4* wr = reinterpret_cast<const float4*>(w1 + (size_t)j * (2 * HIDDEN)) + half * 64;
        float s = 0.f;
#pragma unroll 8
        for (int k = 0; k < 64; ++k) {
            const float4 xk = xr[k];
            const float4 wk = wr[k];
            s += xk.x * wk.x + xk.y * wk.y + xk.z * wk.z + xk.w * wk.w;
        }
        s += __shfl_xor(s, 1);
        if (half == 0) { s += b1[j]; y1_lds[r][j] = fminf(fmaxf(s, 0.f), 1.f); }
    }
    __syncthreads();
    if (tid < 4 * 32) {
        const int r = tid >> 5;
        const int j = tid & 31;
        const float* wr = w2 + j * 32;
        float s = b2[j];
#pragma unroll
        for (int k = 0; k < 32; ++k) s += y1_lds[r][k] * wr[k];
        y2_lds[r][j] = fminf(fmaxf(s, 0.f), 1.f);
    }
    __syncthreads();
    if (tid < 4) {
        const int r = tid;
        float s = b3[0];
#pragma unroll
        for (int k = 0; k < 32; ++k) s += y2_lds[r][k] * w3[k];
        out[blockIdx.x * 4 + r] = tanhf(s);
    }
}

extern "C" void kernel_launch(void* const* d_in, const int* in_sizes, int n_in,
                              void* d_out, int out_size, void* d_ws, size_t ws_size,
                              hipStream_t stream) {
    const int*   us   = (const int*)  d_in[0];
    const int*   them = (const int*)  d_in[1];
    const float* emb  = (const float*)d_in[2];
    const float* w1   = (const float*)d_in[3];
    const float* b1   = (const float*)d_in[4];
    const float* w2   = (const float*)d_in[5];
    const float* b2   = (const float*)d_in[6];
    const float* w3   = (const float*)d_in[7];
    const float* b3   = (const float*)d_in[8];
    float* out = (float*)d_out;

    const int batch = in_sizes[0] / BAG;                       // 8192
    const size_t p_bytes = (size_t)FEAT * NJ * sizeof(float);  // 10.5 MB

    if (ws_size >= p_bytes) {
        float* P = (float*)d_ws;
        const int grid0 = (FEAT + 63) / 64;                    // 642
        k0_project_mfma<<<grid0, 256, 0, stream>>>(emb, w1, P);
        k1_gather_mlp<<<batch / 4, 256, 0, stream>>>(us, them, P,
                                                     b1, w2, b2, w3, b3, out);
    } else {
        nnue_fused<<<(batch + 3) / 4, 256, 0, stream>>>(us, them, emb,
                                                        w1, b1, w2, b2, w3, b3, out);
    }
}

// Round 8
// 27.266 us; speedup vs baseline: 1.8190x; 1.0610x over previous
//
#include <hip/hip_runtime.h>
#include <hip/hip_bf16.h>

constexpr int HIDDEN = 256;
constexpr int BAG    = 32;
constexpr int FEAT   = 41025;   // FEATURE_COUNT + 1 (includes zero pad row)
constexpr int NJ     = 64;      // P columns: [0:32]=us-proj, [32:64]=them-proj
constexpr int LDSS   = 264;     // ushort stride per LDS row (256 + 8 pad, odd quad count)

using bf16x8 = __attribute__((ext_vector_type(8))) short;
using f32x4  = __attribute__((ext_vector_type(4))) float;

__device__ inline unsigned short f2bf(float f) {   // fp32 -> bf16 RNE
    __hip_bfloat16 h = __float2bfloat16(f);        // compiler can fuse pairs to v_cvt_pk_bf16_f32
    return __builtin_bit_cast(unsigned short, h);
}
__device__ inline void cvt_store(unsigned short* dst, float4 v) {
    ushort4 b; b.x = f2bf(v.x); b.y = f2bf(v.y); b.z = f2bf(v.z); b.w = f2bf(v.w);
    *reinterpret_cast<ushort4*>(dst) = b;          // 8B aligned (row offset 528B, kq4*8)
}

// ---------- k0: P = emb @ W2d via bf16 MFMA (fp32 accumulate) ----------
// W2d[k][j] = fc1_w[j&31][(j>>5)*256 + k].  Block = 64 rows x 64 cols, 4 waves.
// Staging is phase-split: issue ALL 32 global loads into registers first
// (32 outstanding dwordx4/thread -> BW-bound), then convert+ds_write.
__global__ __launch_bounds__(256, 2) void k0_project_mfma(
    const float* __restrict__ emb,
    const float* __restrict__ fc1_w,
    float*       __restrict__ P)
{
    __shared__ unsigned short a_lds[64 * LDSS];   // A: [row][k] bf16
    __shared__ unsigned short b_lds[64 * LDSS];   // B: [n(col j)][k] bf16

    const int tid = threadIdx.x;
    const int f0  = blockIdx.x * 64;
    const float4* emb4 = reinterpret_cast<const float4*>(emb);
    const float4* w4   = reinterpret_cast<const float4*>(fc1_w);

    // ---- phase 1: issue all loads (A: 64 rows x 64 float4; B: fc1_w 4096 float4)
    float4 aR[16], bR[16];
#pragma unroll
    for (int s = 0; s < 16; ++s) {
        const int idx4 = s * 256 + tid;        // 0..4095
        const int row  = idx4 >> 6;            // 64 float4s per emb row
        const int kq4  = idx4 & 63;
        int grow = f0 + row; if (grow >= FEAT) grow = FEAT - 1;   // clamp (no OOB)
        aR[s] = emb4[(size_t)grow * 64 + kq4];
    }
#pragma unroll
    for (int s = 0; s < 16; ++s)
        bR[s] = w4[s * 256 + tid];

    // ---- phase 2: convert + LDS write (loads drain incrementally via vmcnt)
#pragma unroll
    for (int s = 0; s < 16; ++s) {
        const int idx4 = s * 256 + tid;
        const int row  = idx4 >> 6;
        const int kq4  = idx4 & 63;
        cvt_store(&a_lds[row * LDSS + kq4 * 4], aR[s]);
    }
#pragma unroll
    for (int s = 0; s < 16; ++s) {
        const int idx4 = s * 256 + tid;
        const int jr  = idx4 >> 7;             // fc1_w row 0..31 (128 float4/row)
        const int kc4 = idx4 & 127;            // float4 within that row
        const int j   = jr + ((kc4 >= 64) ? 32 : 0);   // W2d column
        const int k4  = kc4 & 63;
        cvt_store(&b_lds[j * LDSS + k4 * 4], bR[s]);
    }
    __syncthreads();

    const int lane = tid & 63, wave = tid >> 6;
    const int g = lane >> 4, ml = lane & 15;
    const int mw = wave * 16;                  // wave's 16 rows

    f32x4 acc[4] = {{0.f,0.f,0.f,0.f},{0.f,0.f,0.f,0.f},
                    {0.f,0.f,0.f,0.f},{0.f,0.f,0.f,0.f}};
#pragma unroll
    for (int kt = 0; kt < 8; ++kt) {           // K = 8 x 32
        const bf16x8 af = *reinterpret_cast<const bf16x8*>(
            &a_lds[(mw + ml) * LDSS + kt * 32 + g * 8]);
#pragma unroll
        for (int nt = 0; nt < 4; ++nt) {
            const bf16x8 bf = *reinterpret_cast<const bf16x8*>(
                &b_lds[(nt * 16 + ml) * LDSS + kt * 32 + g * 8]);
            acc[nt] = __builtin_amdgcn_mfma_f32_16x16x32_bf16(af, bf, acc[nt], 0, 0, 0);
        }
    }

    // D layout: row = g*4 + r, col = ml (verified C/D mapping)
#pragma unroll
    for (int nt = 0; nt < 4; ++nt) {
#pragma unroll
        for (int r = 0; r < 4; ++r) {
            const int f = f0 + mw + g * 4 + r;
            if (f < FEAT)
                P[(size_t)f * NJ + nt * 16 + ml] = acc[nt][r];
        }
    }
}

// ---------- k1: gather P rows (128 B each) + fused MLP. One wave per batch row.
__global__ __launch_bounds__(256) void k1_gather_mlp(
    const int*   __restrict__ us,
    const int*   __restrict__ them,
    const float* __restrict__ P,
    const float* __restrict__ b1,
    const float* __restrict__ w2, const float* __restrict__ b2,
    const float* __restrict__ w3, const float* __restrict__ b3,
    float*       __restrict__ out)
{
    __shared__ float w2_lds[32][33];
    __shared__ float y1_lds[4][32];

    const int tid  = threadIdx.x;
    const int wave = tid >> 6;
    const int lane = tid & 63;

    for (int k = tid; k < 32 * 32; k += 256)
        w2_lds[k >> 5][k & 31] = w2[k];
    __syncthreads();

    const int row = blockIdx.x * 4 + wave;
    int idx;
    {
        const int* up = us   + (size_t)row * BAG;
        const int* tp = them + (size_t)row * BAG;
        idx = (lane < BAG) ? up[lane] : tp[lane - BAG];
    }

    float acc = 0.f;
    const int srcbase = lane & 32;
#pragma unroll
    for (int i = 0; i < BAG; ++i) {
        const int f = __shfl(idx, srcbase + i);
        acc += P[(size_t)f * NJ + lane];
    }
    acc += __shfl_xor(acc, 32);

    if (lane < 32)
        y1_lds[wave][lane] = fminf(fmaxf(acc + b1[lane], 0.f), 1.f);
    __syncthreads();

    float r3 = 0.f;
    if (lane < 32) {
        float s = b2[lane];
#pragma unroll
        for (int k = 0; k < 32; ++k) s += y1_lds[wave][k] * w2_lds[lane][k];
        r3 = fminf(fmaxf(s, 0.f), 1.f) * w3[lane];
    }
    r3 += __shfl_xor(r3, 16); r3 += __shfl_xor(r3, 8); r3 += __shfl_xor(r3, 4);
    r3 += __shfl_xor(r3, 2);  r3 += __shfl_xor(r3, 1);
    if (lane == 0) out[row] = tanhf(r3 + b3[0]);
}

// ---------- fallback: R0 monolithic kernel (if ws too small) ----------
__global__ __launch_bounds__(256) void nnue_fused(
    const int*   __restrict__ us,
    const int*   __restrict__ them,
    const float* __restrict__ emb,
    const float* __restrict__ w1, const float* __restrict__ b1,
    const float* __restrict__ w2, const float* __restrict__ b2,
    const float* __restrict__ w3, const float* __restrict__ b3,
    float*       __restrict__ out)
{
    __shared__ float x_lds[4][2 * HIDDEN];
    __shared__ float y1_lds[4][32];
    __shared__ float y2_lds[4][32];

    const int tid  = threadIdx.x;
    const int wave = tid >> 6;
    const int lane = tid & 63;
    const int row  = blockIdx.x * 4 + wave;

    int myidx;
    {
        const int* up = us   + (size_t)row * BAG;
        const int* tp = them + (size_t)row * BAG;
        myidx = (lane < BAG) ? up[lane] : tp[lane - BAG];
    }
    const float4* emb4 = reinterpret_cast<const float4*>(emb);
    float4 accU = make_float4(0.f, 0.f, 0.f, 0.f);
    float4 accT = make_float4(0.f, 0.f, 0.f, 0.f);
#pragma unroll
    for (int i = 0; i < BAG; ++i) {
        const int iu = __shfl(myidx, i);
        const int it = __shfl(myidx, BAG + i);
        const float4 vu = emb4[(size_t)iu * (HIDDEN / 4) + lane];
        const float4 vt = emb4[(size_t)it * (HIDDEN / 4) + lane];
        accU.x += vu.x; accU.y += vu.y; accU.z += vu.z; accU.w += vu.w;
        accT.x += vt.x; accT.y += vt.y; accT.z += vt.z; accT.w += vt.w;
    }
    {
        float4* xv = reinterpret_cast<float4*>(&x_lds[wave][0]);
        xv[lane]      = accU;
        xv[64 + lane] = accT;
    }
    __syncthreads();
    {
        const int r    = tid >> 6;
        const int sub  = tid & 63;
        const int j    = sub >> 1;
        const int half = sub & 1;
        const float4* xr = reinterpret_cast<const float4*>(&x_lds[r][0]) + half * 64;
        const float4* wr = reinterpret_cast<const float4*>(w1 + (size_t)j * (2 * HIDDEN)) + half * 64;
        float s = 0.f;
#pragma unroll 8
        for (int k = 0; k < 64; ++k) {
            const float4 xk = xr[k];
            const float4 wk = wr[k];
            s += xk.x * wk.x + xk.y * wk.y + xk.z * wk.z + xk.w * wk.w;
        }
        s += __shfl_xor(s, 1);
        if (half == 0) { s += b1[j]; y1_lds[r][j] = fminf(fmaxf(s, 0.f), 1.f); }
    }
    __syncthreads();
    if (tid < 4 * 32) {
        const int r = tid >> 5;
        const int j = tid & 31;
        const float* wr = w2 + j * 32;
        float s = b2[j];
#pragma unroll
        for (int k = 0; k < 32; ++k) s += y1_lds[r][k] * wr[k];
        y2_lds[r][j] = fminf(fmaxf(s, 0.f), 1.f);
    }
    __syncthreads();
    if (tid < 4) {
        const int r = tid;
        float s = b3[0];
#pragma unroll
        for (int k = 0; k < 32; ++k) s += y2_lds[r][k] * w3[k];
        out[blockIdx.x * 4 + r] = tanhf(s);
    }
}

extern "C" void kernel_launch(void* const* d_in, const int* in_sizes, int n_in,
                              void* d_out, int out_size, void* d_ws, size_t ws_size,
                              hipStream_t stream) {
    const int*   us   = (const int*)  d_in[0];
    const int*   them = (const int*)  d_in[1];
    const float* emb  = (const float*)d_in[2];
    const float* w1   = (const float*)d_in[3];
    const float* b1   = (const float*)d_in[4];
    const float* w2   = (const float*)d_in[5];
    const float* b2   = (const float*)d_in[6];
    const float* w3   = (const float*)d_in[7];
    const float* b3   = (const float*)d_in[8];
    float* out = (float*)d_out;

    const int batch = in_sizes[0] / BAG;                       // 8192
    const size_t p_bytes = (size_t)FEAT * NJ * sizeof(float);  // 10.5 MB

    if (ws_size >= p_bytes) {
        float* P = (float*)d_ws;
        const int grid0 = (FEAT + 63) / 64;                    // 642
        k0_project_mfma<<<grid0, 256, 0, stream>>>(emb, w1, P);
        k1_gather_mlp<<<batch / 4, 256, 0, stream>>>(us, them, P,
                                                     b1, w2, b2, w3, b3, out);
    } else {
        nnue_fused<<<(batch + 3) / 4, 256, 0, stream>>>(us, them, emb,
                                                        w1, b1, w2, b2, w3, b3, out);
    }
}